// Round 1
// baseline (205.857 us; speedup 1.0000x reference)
//
#include <hip/hip_runtime.h>
#include <hip/hip_bf16.h>

#define EMB 768
#define NH 8
#define DH 96
#define BATCH 8
#define SEQ 1024
#define M_TOT (BATCH * SEQ)   // 8192 rows of x
#define NCOLS (3 * EMB)       // q(768) | k(768) | v(768) output channels

typedef float f32x4 __attribute__((ext_vector_type(4)));
typedef __bf16 bf16x8 __attribute__((ext_vector_type(8)));

__device__ __forceinline__ unsigned short f2bf_bits(float f) {
  __hip_bfloat16 b = __float2bfloat16(f);
  return *reinterpret_cast<unsigned short*>(&b);
}

__device__ __forceinline__ void gload_lds16(const void* g, void* l) {
  // async global->LDS, 16B per lane; LDS dest must be wave-uniform base (+lane*16 by HW)
  __builtin_amdgcn_global_load_lds(
      (__attribute__((address_space(1))) void*)(g),
      (__attribute__((address_space(3))) void*)(l), 16, 0, 0);
}

// ---------------- prep: x fp32 -> bf16 ----------------
__global__ void prep_x_kernel(const float* __restrict__ x, __hip_bfloat16* __restrict__ xb) {
  const int n4 = M_TOT * EMB / 4;
  int i = blockIdx.x * blockDim.x + threadIdx.x;
  if (i < n4) {
    f32x4 v = reinterpret_cast<const f32x4*>(x)[i];
    ushort4 o;
    o.x = f2bf_bits(v[0]);
    o.y = f2bf_bits(v[1]);
    o.z = f2bf_bits(v[2]);
    o.w = f2bf_bits(v[3]);
    reinterpret_cast<ushort4*>(xb)[i] = o;
  }
}

// ---------------- prep: permuted weights -> bf16, bias fp32 ----------------
// Wall rows: [0,768)   = q channel h*96+d  <- qkv_w row h*192+2d, scaled 1/sqrt(768)
//            [768,1536)= k channel          <- qkv_w row h*192+2d+1
//            [1536,2304)= v                 <- val_w
__global__ void prep_w_kernel(const float* __restrict__ qkv_w, const float* __restrict__ qkv_b,
                              const float* __restrict__ val_w, const float* __restrict__ val_b,
                              __hip_bfloat16* __restrict__ Wall, float* __restrict__ bias) {
  const float inv_s = 0.03608439182435161f;  // 1/sqrt(768)
  int idx = blockIdx.x * 256 + threadIdx.x;
  if (idx >= NCOLS * EMB) return;
  int r = idx / EMB;
  int c = idx - r * EMB;
  float v;
  if (r < EMB) {
    int h = r / DH, d = r - h * DH;
    int src = h * 192 + 2 * d;
    v = qkv_w[(size_t)src * EMB + c] * inv_s;
    if (c == 0) bias[r] = qkv_b[src] * inv_s;
  } else if (r < 2 * EMB) {
    int r2 = r - EMB;
    int h = r2 / DH, d = r2 - h * DH;
    int src = h * 192 + 2 * d + 1;
    v = qkv_w[(size_t)src * EMB + c];
    if (c == 0) bias[r] = qkv_b[src];
  } else {
    int r3 = r - 2 * EMB;
    v = val_w[(size_t)r3 * EMB + c];
    if (c == 0) bias[r] = val_b[r3];
  }
  Wall[idx] = __float2bfloat16(v);
}

// ---------------- fused projection GEMM ----------------
// C[8192 x 2304] = xb @ Wall^T + bias.  cols [0,768)->q_ws bf16, [768,1536)->k_ws bf16,
// [1536,2304)->vout fp32.  128x128 tile, BK=32, 4 waves (2x2 of 64x64), mfma 16x16x32 bf16.
__global__ __launch_bounds__(256) void gemm_kernel(
    const __hip_bfloat16* __restrict__ xb, const __hip_bfloat16* __restrict__ Wall,
    const float* __restrict__ bias, __hip_bfloat16* __restrict__ q_ws,
    __hip_bfloat16* __restrict__ k_ws, float* __restrict__ vout) {
  __shared__ __hip_bfloat16 As[128 * 32];
  __shared__ __hip_bfloat16 Bs[128 * 32];
  const int tid = threadIdx.x;
  const int w = tid >> 6, l = tid & 63;
  const int m0 = blockIdx.x * 128;
  const int n0 = blockIdx.y * 128;
  const int wr = w >> 1, wc = w & 1;

  f32x4 acc[4][4] = {};

  // staging geometry: per wave 2 chunks of 1KB per matrix; lane l covers bytes [l*16,l*16+16)
  const int sr0 = (w * 2 + 0) * 16 + (l >> 2);
  const int sr1 = (w * 2 + 1) * 16 + (l >> 2);
  const int sc = (l & 3) * 8;  // k-element offset within 32

  for (int kt = 0; kt < EMB / 32; ++kt) {
    const int k0 = kt * 32;
    gload_lds16(xb + (size_t)(m0 + sr0) * EMB + k0 + sc, (void*)(As + (w * 2 + 0) * 512));
    gload_lds16(xb + (size_t)(m0 + sr1) * EMB + k0 + sc, (void*)(As + (w * 2 + 1) * 512));
    gload_lds16(Wall + (size_t)(n0 + sr0) * EMB + k0 + sc, (void*)(Bs + (w * 2 + 0) * 512));
    gload_lds16(Wall + (size_t)(n0 + sr1) * EMB + k0 + sc, (void*)(Bs + (w * 2 + 1) * 512));
    __syncthreads();  // drains vmcnt before barrier -> LDS tile ready

    bf16x8 af[4], bfr[4];
#pragma unroll
    for (int t = 0; t < 4; ++t) {
      af[t] = *reinterpret_cast<const bf16x8*>(As + (wr * 64 + t * 16 + (l & 15)) * 32 + (l >> 4) * 8);
      bfr[t] = *reinterpret_cast<const bf16x8*>(Bs + (wc * 64 + t * 16 + (l & 15)) * 32 + (l >> 4) * 8);
    }
#pragma unroll
    for (int i = 0; i < 4; ++i)
#pragma unroll
      for (int j = 0; j < 4; ++j)
        acc[i][j] = __builtin_amdgcn_mfma_f32_16x16x32_bf16(af[i], bfr[j], acc[i][j], 0, 0, 0);
    __syncthreads();  // all ds_reads done before next stage overwrites
  }

  // epilogue: C layout col = l&15, row = (l>>4)*4 + q   (verified m89 mapping)
  const int rowbase = m0 + wr * 64;
  const int colbase = n0 + wc * 64;
#pragma unroll
  for (int j = 0; j < 4; ++j) {
    const int n = colbase + j * 16 + (l & 15);
    const float bb = bias[n];
#pragma unroll
    for (int i = 0; i < 4; ++i) {
#pragma unroll
      for (int q = 0; q < 4; ++q) {
        const int m = rowbase + i * 16 + (l >> 4) * 4 + q;
        const float v = acc[i][j][q] + bb;
        if (n0 >= 2 * EMB) {
          vout[(size_t)m * EMB + (n - 2 * EMB)] = v;
        } else if (n0 >= EMB) {
          k_ws[(size_t)m * EMB + (n - EMB)] = __float2bfloat16(v);
        } else {
          q_ws[(size_t)m * EMB + n] = __float2bfloat16(v);
        }
      }
    }
  }
}

// ---------------- fused QK^T + softmax ----------------
// grid (SEQ/16, BATCH*NH); block 256 (4 waves). Each block: 16 q-rows x 1024 k-cols.
// q already scaled by 1/sqrt(768) (folded into Wq/bq).
__global__ __launch_bounds__(256) void attn_kernel(
    const __hip_bfloat16* __restrict__ q_ws, const __hip_bfloat16* __restrict__ k_ws,
    const float* __restrict__ rel, float* __restrict__ eout) {
  __shared__ float S[16 * 1024];  // 64 KB scores tile
  const int tid = threadIdx.x;
  const int w = tid >> 6, l = tid & 63;
  const int rb = blockIdx.x;
  const int bh = blockIdx.y;
  const int b = bh >> 3, h = bh & 7;
  const int row0 = rb * 16;

  // ---- phase 1: scores via MFMA ----
  const __hip_bfloat16* qbase = q_ws + ((size_t)(b * SEQ + row0)) * EMB + h * DH;
  const __hip_bfloat16* kbase0 = k_ws + ((size_t)(b * SEQ)) * EMB + h * DH;

  bf16x8 qf[3];
#pragma unroll
  for (int kc = 0; kc < 3; ++kc)
    qf[kc] = *reinterpret_cast<const bf16x8*>(qbase + (size_t)(l & 15) * EMB + kc * 32 + (l >> 4) * 8);

  for (int ct = 0; ct < 16; ++ct) {
    const int ctg = w * 16 + ct;  // global col-tile
    const __hip_bfloat16* kb = kbase0 + (size_t)(ctg * 16 + (l & 15)) * EMB;
    f32x4 acc = {0.f, 0.f, 0.f, 0.f};
#pragma unroll
    for (int kc = 0; kc < 3; ++kc) {
      bf16x8 kf = *reinterpret_cast<const bf16x8*>(kb + kc * 32 + (l >> 4) * 8);
      acc = __builtin_amdgcn_mfma_f32_16x16x32_bf16(qf[kc], kf, acc, 0, 0, 0);
    }
    const int col = ctg * 16 + (l & 15);
#pragma unroll
    for (int jj = 0; jj < 4; ++jj)
      S[((l >> 4) * 4 + jj) * 1024 + col] = acc[jj];
  }
  __syncthreads();

  // ---- phase 2: softmax, 16 lanes per row (wave w owns rows 4w..4w+3) ----
  const int row = (w << 2) + (l >> 4);  // 0..15
  const int sub = l & 15;
  const int rowg = row0 + row;
  float* srow = S + row * 1024;
  const float* relrow = rel + ((size_t)h * SEQ + rowg) * SEQ;

  float mx = -3.4e38f;
#pragma unroll
  for (int k = 0; k < 16; ++k) {
    const int col = sub * 4 + k * 64;
    f32x4 v = *reinterpret_cast<f32x4*>(srow + col);
    f32x4 r = *reinterpret_cast<const f32x4*>(relrow + col);
    v = v + r;
    *reinterpret_cast<f32x4*>(srow + col) = v;
    mx = fmaxf(mx, fmaxf(fmaxf(v[0], v[1]), fmaxf(v[2], v[3])));
  }
#pragma unroll
  for (int off = 1; off < 16; off <<= 1) mx = fmaxf(mx, __shfl_xor(mx, off));

  float sum = 0.f;
#pragma unroll
  for (int k = 0; k < 16; ++k) {
    const int col = sub * 4 + k * 64;
    f32x4 v = *reinterpret_cast<f32x4*>(srow + col);
    f32x4 e;
    e[0] = __expf(v[0] - mx);
    e[1] = __expf(v[1] - mx);
    e[2] = __expf(v[2] - mx);
    e[3] = __expf(v[3] - mx);
    *reinterpret_cast<f32x4*>(srow + col) = e;
    sum += e[0] + e[1] + e[2] + e[3];
  }
#pragma unroll
  for (int off = 1; off < 16; off <<= 1) sum += __shfl_xor(sum, off);
  const float rinv = 1.0f / sum;

  float* orow = eout + ((size_t)bh * SEQ + rowg) * SEQ;
#pragma unroll
  for (int k = 0; k < 16; ++k) {
    const int col = sub * 4 + k * 64;
    f32x4 v = *reinterpret_cast<f32x4*>(srow + col);
    v = v * rinv;
    *reinterpret_cast<f32x4*>(orow + col) = v;
  }
}

extern "C" void kernel_launch(void* const* d_in, const int* in_sizes, int n_in,
                              void* d_out, int out_size, void* d_ws, size_t ws_size,
                              hipStream_t stream) {
  const float* x = (const float*)d_in[0];
  const float* rel = (const float*)d_in[1];
  const float* qkv_w = (const float*)d_in[2];
  const float* qkv_b = (const float*)d_in[3];
  const float* val_w = (const float*)d_in[4];
  const float* val_b = (const float*)d_in[5];
  float* out = (float*)d_out;

  char* ws = (char*)d_ws;
  // workspace layout (bytes), all 16B-aligned
  __hip_bfloat16* xb = (__hip_bfloat16*)(ws);                  // 12,582,912
  __hip_bfloat16* Wall = (__hip_bfloat16*)(ws + 12582912);     //  3,538,944
  float* bias = (float*)(ws + 16121856);                       //      9,216
  __hip_bfloat16* q_ws = (__hip_bfloat16*)(ws + 16131072);     // 12,582,912
  __hip_bfloat16* k_ws = (__hip_bfloat16*)(ws + 28713984);     // 12,582,912
  // total 41,296,896 bytes

  float* vout = out;                  // [8192][768] values
  float* eout = out + (size_t)M_TOT * EMB;  // [64][1024][1024] energy

  prep_x_kernel<<<dim3(M_TOT * EMB / 4 / 256), dim3(256), 0, stream>>>(x, xb);
  prep_w_kernel<<<dim3(NCOLS * EMB / 256), dim3(256), 0, stream>>>(qkv_w, qkv_b, val_w, val_b,
                                                                   Wall, bias);
  gemm_kernel<<<dim3(M_TOT / 128, NCOLS / 128), dim3(256), 0, stream>>>(xb, Wall, bias, q_ws,
                                                                        k_ws, vout);
  attn_kernel<<<dim3(SEQ / 16, BATCH * NH), dim3(256), 0, stream>>>(q_ws, k_ws, rel, eout);
}

// Round 2
// 204.414 us; speedup vs baseline: 1.0071x; 1.0071x over previous
//
#include <hip/hip_runtime.h>
#include <hip/hip_bf16.h>

#define EMB 768
#define NH 8
#define DH 96
#define BATCH 8
#define SEQ 1024
#define M_TOT (BATCH * SEQ)   // 8192 rows of x
#define NCOLS (3 * EMB)       // q(768) | k(768) | v(768) output channels

typedef float f32x4 __attribute__((ext_vector_type(4)));
typedef __bf16 bf16x8 __attribute__((ext_vector_type(8)));

__device__ __forceinline__ unsigned short f2bf_bits(float f) {
  __hip_bfloat16 b = __float2bfloat16(f);
  return *reinterpret_cast<unsigned short*>(&b);
}

__device__ __forceinline__ void gload_lds16(const void* g, void* l) {
  // async global->LDS, 16B per lane; LDS dest must be wave-uniform base (+lane*16 by HW)
  __builtin_amdgcn_global_load_lds(
      (__attribute__((address_space(1))) void*)(g),
      (__attribute__((address_space(3))) void*)(l), 16, 0, 0);
}

// ---------------- prep: x fp32 -> bf16 ----------------
__global__ void prep_x_kernel(const float* __restrict__ x, __hip_bfloat16* __restrict__ xb) {
  const int n4 = M_TOT * EMB / 4;
  int i = blockIdx.x * blockDim.x + threadIdx.x;
  if (i < n4) {
    f32x4 v = reinterpret_cast<const f32x4*>(x)[i];
    ushort4 o;
    o.x = f2bf_bits(v[0]);
    o.y = f2bf_bits(v[1]);
    o.z = f2bf_bits(v[2]);
    o.w = f2bf_bits(v[3]);
    reinterpret_cast<ushort4*>(xb)[i] = o;
  }
}

// ---------------- prep: permuted weights -> bf16, bias fp32 ----------------
__global__ void prep_w_kernel(const float* __restrict__ qkv_w, const float* __restrict__ qkv_b,
                              const float* __restrict__ val_w, const float* __restrict__ val_b,
                              __hip_bfloat16* __restrict__ Wall, float* __restrict__ bias) {
  const float inv_s = 0.03608439182435161f;  // 1/sqrt(768)
  int idx = blockIdx.x * 256 + threadIdx.x;
  if (idx >= NCOLS * EMB) return;
  int r = idx / EMB;
  int c = idx - r * EMB;
  float v;
  if (r < EMB) {
    int h = r / DH, d = r - h * DH;
    int src = h * 192 + 2 * d;
    v = qkv_w[(size_t)src * EMB + c] * inv_s;
    if (c == 0) bias[r] = qkv_b[src] * inv_s;
  } else if (r < 2 * EMB) {
    int r2 = r - EMB;
    int h = r2 / DH, d = r2 - h * DH;
    int src = h * 192 + 2 * d + 1;
    v = qkv_w[(size_t)src * EMB + c];
    if (c == 0) bias[r] = qkv_b[src];
  } else {
    int r3 = r - 2 * EMB;
    v = val_w[(size_t)r3 * EMB + c];
    if (c == 0) bias[r] = val_b[r3];
  }
  Wall[idx] = __float2bfloat16(v);
}

// ---------------- fused projection GEMM (m97-structure, 128x128, BK=32) ----------------
__global__ __launch_bounds__(256) void gemm_kernel(
    const __hip_bfloat16* __restrict__ xb, const __hip_bfloat16* __restrict__ Wall,
    const float* __restrict__ bias, __hip_bfloat16* __restrict__ q_ws,
    __hip_bfloat16* __restrict__ k_ws, float* __restrict__ vout) {
  __shared__ __hip_bfloat16 As[128 * 32];
  __shared__ __hip_bfloat16 Bs[128 * 32];
  const int tid = threadIdx.x;
  const int w = tid >> 6, l = tid & 63;
  const int m0 = blockIdx.x * 128;
  const int n0 = blockIdx.y * 128;
  const int wr = w >> 1, wc = w & 1;

  f32x4 acc[4][4] = {};

  const int sr0 = (w * 2 + 0) * 16 + (l >> 2);
  const int sr1 = (w * 2 + 1) * 16 + (l >> 2);
  const int sc = (l & 3) * 8;

  for (int kt = 0; kt < EMB / 32; ++kt) {
    const int k0 = kt * 32;
    gload_lds16(xb + (size_t)(m0 + sr0) * EMB + k0 + sc, (void*)(As + (w * 2 + 0) * 512));
    gload_lds16(xb + (size_t)(m0 + sr1) * EMB + k0 + sc, (void*)(As + (w * 2 + 1) * 512));
    gload_lds16(Wall + (size_t)(n0 + sr0) * EMB + k0 + sc, (void*)(Bs + (w * 2 + 0) * 512));
    gload_lds16(Wall + (size_t)(n0 + sr1) * EMB + k0 + sc, (void*)(Bs + (w * 2 + 1) * 512));
    __syncthreads();

    bf16x8 af[4], bfr[4];
#pragma unroll
    for (int t = 0; t < 4; ++t) {
      af[t] = *reinterpret_cast<const bf16x8*>(As + (wr * 64 + t * 16 + (l & 15)) * 32 + (l >> 4) * 8);
      bfr[t] = *reinterpret_cast<const bf16x8*>(Bs + (wc * 64 + t * 16 + (l & 15)) * 32 + (l >> 4) * 8);
    }
#pragma unroll
    for (int i = 0; i < 4; ++i)
#pragma unroll
      for (int j = 0; j < 4; ++j)
        acc[i][j] = __builtin_amdgcn_mfma_f32_16x16x32_bf16(af[i], bfr[j], acc[i][j], 0, 0, 0);
    __syncthreads();
  }

  const int rowbase = m0 + wr * 64;
  const int colbase = n0 + wc * 64;
#pragma unroll
  for (int j = 0; j < 4; ++j) {
    const int n = colbase + j * 16 + (l & 15);
    const float bb = bias[n];
#pragma unroll
    for (int i = 0; i < 4; ++i) {
#pragma unroll
      for (int q = 0; q < 4; ++q) {
        const int m = rowbase + i * 16 + (l >> 4) * 4 + q;
        const float v = acc[i][j][q] + bb;
        if (n0 >= 2 * EMB) {
          vout[(size_t)m * EMB + (n - 2 * EMB)] = v;
        } else if (n0 >= EMB) {
          k_ws[(size_t)m * EMB + (n - EMB)] = __float2bfloat16(v);
        } else {
          q_ws[(size_t)m * EMB + n] = __float2bfloat16(v);
        }
      }
    }
  }
}

// ---------------- fused QK^T + softmax, scores held in registers ----------------
// grid (SEQ/16, BATCH*NH); 256 threads = 4 waves. Block: 16 q-rows x 1024 k-cols.
// Wave w owns cols [w*256, w*256+256) as 16 MFMA col-tiles; lane holds
// acc[ct][j] = score(row0 + (l>>4)*4 + j, w*256 + ct*16 + (l&15)).
// Row reductions: 16 values in-lane -> shfl_xor over 16-lane group -> 512B LDS
// cross-wave combine (2 barriers). Single global read (rel) + write (energy) pass.
__global__ __launch_bounds__(256) void attn_kernel(
    const __hip_bfloat16* __restrict__ q_ws, const __hip_bfloat16* __restrict__ k_ws,
    const float* __restrict__ rel, float* __restrict__ eout) {
  __shared__ float redmax[16][4];
  __shared__ float redsum[16][4];
  const int tid = threadIdx.x;
  const int w = tid >> 6, l = tid & 63;
  const int rb = blockIdx.x;
  const int bh = blockIdx.y;
  const int b = bh >> 3, h = bh & 7;
  const int row0 = rb * 16;
  const int lr = l >> 4;   // row group 0..3 (rows lr*4..lr*4+3)
  const int lc = l & 15;   // col within 16-wide tile

  // ---- q fragments (q pre-scaled by 1/sqrt(768) in the GEMM) ----
  const __hip_bfloat16* qbase = q_ws + ((size_t)(b * SEQ + row0)) * EMB + h * DH;
  bf16x8 qf[3];
#pragma unroll
  for (int kc = 0; kc < 3; ++kc)
    qf[kc] = *reinterpret_cast<const bf16x8*>(qbase + (size_t)lc * EMB + kc * 32 + lr * 8);

  // ---- QK^T into registers ----
  const __hip_bfloat16* kbase =
      k_ws + ((size_t)(b * SEQ + w * 256 + lc)) * EMB + h * DH;
  f32x4 acc[16];
#pragma unroll
  for (int ct = 0; ct < 16; ++ct) {
    const __hip_bfloat16* kb = kbase + (size_t)(ct * 16) * EMB;
    f32x4 a = {0.f, 0.f, 0.f, 0.f};
#pragma unroll
    for (int kc = 0; kc < 3; ++kc) {
      bf16x8 kf = *reinterpret_cast<const bf16x8*>(kb + kc * 32 + lr * 8);
      a = __builtin_amdgcn_mfma_f32_16x16x32_bf16(qf[kc], kf, a, 0, 0, 0);
    }
    acc[ct] = a;
  }

  // ---- add rel_pos, per-row max ----
  const float* relp = rel + ((size_t)h * SEQ + row0 + lr * 4) * SEQ + w * 256 + lc;
  float mx[4] = {-3.4e38f, -3.4e38f, -3.4e38f, -3.4e38f};
#pragma unroll
  for (int ct = 0; ct < 16; ++ct) {
#pragma unroll
    for (int j = 0; j < 4; ++j) {
      float r = relp[(size_t)j * SEQ + ct * 16];
      acc[ct][j] += r;
      mx[j] = fmaxf(mx[j], acc[ct][j]);
    }
  }
#pragma unroll
  for (int j = 0; j < 4; ++j) {
#pragma unroll
    for (int off = 1; off < 16; off <<= 1) mx[j] = fmaxf(mx[j], __shfl_xor(mx[j], off));
  }
  if (lc == 0) {
#pragma unroll
    for (int j = 0; j < 4; ++j) redmax[lr * 4 + j][w] = mx[j];
  }
  __syncthreads();
#pragma unroll
  for (int j = 0; j < 4; ++j) {
    const float* rm = redmax[lr * 4 + j];
    mx[j] = fmaxf(fmaxf(rm[0], rm[1]), fmaxf(rm[2], rm[3]));
  }

  // ---- exp, per-row sum ----
  float sm[4] = {0.f, 0.f, 0.f, 0.f};
#pragma unroll
  for (int ct = 0; ct < 16; ++ct) {
#pragma unroll
    for (int j = 0; j < 4; ++j) {
      float e = __expf(acc[ct][j] - mx[j]);
      acc[ct][j] = e;
      sm[j] += e;
    }
  }
#pragma unroll
  for (int j = 0; j < 4; ++j) {
#pragma unroll
    for (int off = 1; off < 16; off <<= 1) sm[j] += __shfl_xor(sm[j], off);
  }
  if (lc == 0) {
#pragma unroll
    for (int j = 0; j < 4; ++j) redsum[lr * 4 + j][w] = sm[j];
  }
  __syncthreads();
  float rinv[4];
#pragma unroll
  for (int j = 0; j < 4; ++j) {
    const float* rs = redsum[lr * 4 + j];
    rinv[j] = 1.0f / (rs[0] + rs[1] + rs[2] + rs[3]);
  }

  // ---- normalized write ----
  float* op = eout + ((size_t)bh * SEQ + row0 + lr * 4) * SEQ + w * 256 + lc;
#pragma unroll
  for (int ct = 0; ct < 16; ++ct) {
#pragma unroll
    for (int j = 0; j < 4; ++j) {
      op[(size_t)j * SEQ + ct * 16] = acc[ct][j] * rinv[j];
    }
  }
}

extern "C" void kernel_launch(void* const* d_in, const int* in_sizes, int n_in,
                              void* d_out, int out_size, void* d_ws, size_t ws_size,
                              hipStream_t stream) {
  const float* x = (const float*)d_in[0];
  const float* rel = (const float*)d_in[1];
  const float* qkv_w = (const float*)d_in[2];
  const float* qkv_b = (const float*)d_in[3];
  const float* val_w = (const float*)d_in[4];
  const float* val_b = (const float*)d_in[5];
  float* out = (float*)d_out;

  char* ws = (char*)d_ws;
  __hip_bfloat16* xb = (__hip_bfloat16*)(ws);                  // 12,582,912
  __hip_bfloat16* Wall = (__hip_bfloat16*)(ws + 12582912);     //  3,538,944
  float* bias = (float*)(ws + 16121856);                       //      9,216
  __hip_bfloat16* q_ws = (__hip_bfloat16*)(ws + 16131072);     // 12,582,912
  __hip_bfloat16* k_ws = (__hip_bfloat16*)(ws + 28713984);     // 12,582,912

  float* vout = out;                       // [8192][768] values
  float* eout = out + (size_t)M_TOT * EMB; // [64][1024][1024] energy

  prep_x_kernel<<<dim3(M_TOT * EMB / 4 / 256), dim3(256), 0, stream>>>(x, xb);
  prep_w_kernel<<<dim3(NCOLS * EMB / 256), dim3(256), 0, stream>>>(qkv_w, qkv_b, val_w, val_b,
                                                                   Wall, bias);
  gemm_kernel<<<dim3(M_TOT / 128, NCOLS / 128), dim3(256), 0, stream>>>(xb, Wall, bias, q_ws,
                                                                        k_ws, vout);
  attn_kernel<<<dim3(SEQ / 16, BATCH * NH), dim3(256), 0, stream>>>(q_ws, k_ws, rel, eout);
}